// Round 7
// baseline (2260.988 us; speedup 1.0000x reference)
//
#include <hip/hip_runtime.h>
#include <hip/hip_bf16.h>

#define SEQ   4096
#define HH    4
#define SCALE 0.125f

// ---- ws layout (float offsets) — total 36.9 MB (< proven-available 70.5 MB) ----
// Established facts: all 9 inputs fp32 (R1 NaN when read as bf16; R2 detector);
// OUTPUT IS FP32 (R6 probe: bf16 write of 4.0 read back as ~0 => float32 view);
// ws_size >= 70.5 MB (R2 high-offset layout == R3 compact layout, bit-identical).
constexpr size_t OFF_WQT = 0;        // 65536 each, fp32 transposed weights
constexpr size_t OFF_WKT = 65536;
constexpr size_t OFF_WVT = 131072;
constexpr size_t OFF_WOT = 196608;
constexpr size_t OFF_M   = 262144;   // [bh*S+j] column max (32768)
constexpr size_t OFF_RZ  = 294912;   // [bh*S+j] 1/Z (32768)
constexpr size_t OFF_PM  = 327680;   // [8][32768] partial max
constexpr size_t OFF_PZ  = 589824;   // [8][32768] partial sumexp
constexpr size_t OFF_AO  = 851968;   // [b*S+i][256] fp32 attn out (atomic acc)
constexpr size_t OFF_Q   = 2949120;  // [bh][s][64] fp32
constexpr size_t OFF_K   = 5046272;
constexpr size_t OFF_V   = 7143424;  // ends at 9240576 floats = 36.96 MB

// ---- zero the atomic-accumulated AO region ----
__global__ void k_zero(float* __restrict__ ws) {
    size_t i = (size_t)blockIdx.x * 1024 + (size_t)threadIdx.x * 4;
    *(float4*)(ws + OFF_AO + i) = make_float4(0.f, 0.f, 0.f, 0.f);
}

// ---- transpose weights to [k][n] fp32 ----
__global__ void k_transpose(const float* __restrict__ wq, const float* __restrict__ wk,
                            const float* __restrict__ wv, const float* __restrict__ wo,
                            float* __restrict__ ws) {
    int kk = blockIdx.x, t = threadIdx.x, y = blockIdx.y;
    const float* src = (y == 0) ? wq : (y == 1) ? wk : (y == 2) ? wv : wo;
    ws[(size_t)y * 65536 + kk * 256 + t] = src[(size_t)t * 256 + kk];
}

// ---- QKV projection: 16 rows/block, thread t owns output column t ----
__global__ __launch_bounds__(256) void k_qkv(const float* __restrict__ x,
                                             const float* __restrict__ bq,
                                             const float* __restrict__ bk,
                                             const float* __restrict__ bv,
                                             float* __restrict__ ws) {
    __shared__ float xs[16 * 768];
    const float* wqT = ws + OFF_WQT;
    const float* wkT = ws + OFF_WKT;
    const float* wvT = ws + OFF_WVT;
    float* Q = ws + OFF_Q; float* K = ws + OFF_K; float* V = ws + OFF_V;
    int t = threadIdx.x;
    int row0 = blockIdx.x * 16;
    for (int idx = t; idx < 16 * 768; idx += 256)
        xs[idx] = x[(size_t)row0 * 768 + idx];
    __syncthreads();

    float aq[16], ak[16], av[16];
#pragma unroll
    for (int r = 0; r < 16; r++) { aq[r] = 0.f; ak[r] = 0.f; av[r] = 0.f; }

    for (int kk = 0; kk < 256; kk += 4) {
        float wq0 = wqT[(kk + 0) * 256 + t], wq1 = wqT[(kk + 1) * 256 + t];
        float wq2 = wqT[(kk + 2) * 256 + t], wq3 = wqT[(kk + 3) * 256 + t];
        float wk0 = wkT[(kk + 0) * 256 + t], wk1 = wkT[(kk + 1) * 256 + t];
        float wk2 = wkT[(kk + 2) * 256 + t], wk3 = wkT[(kk + 3) * 256 + t];
        float wv0 = wvT[(kk + 0) * 256 + t], wv1 = wvT[(kk + 1) * 256 + t];
        float wv2 = wvT[(kk + 2) * 256 + t], wv3 = wvT[(kk + 3) * 256 + t];
#pragma unroll
        for (int r = 0; r < 16; r++) {
            float4 xq = *(const float4*)(xs + r * 768 + kk);
            float4 xk = *(const float4*)(xs + r * 768 + 256 + kk);
            float4 xv = *(const float4*)(xs + r * 768 + 512 + kk);
            aq[r] += xq.x * wq0 + xq.y * wq1 + xq.z * wq2 + xq.w * wq3;
            ak[r] += xk.x * wk0 + xk.y * wk1 + xk.z * wk2 + xk.w * wk3;
            av[r] += xv.x * wv0 + xv.y * wv1 + xv.z * wv2 + xv.w * wv3;
        }
    }
    float biasq = bq[t], biask = bk[t], biasv = bv[t];
    int h = t >> 6, d = t & 63;
#pragma unroll
    for (int r = 0; r < 16; r++) {
        int row = row0 + r;
        int b = row >> 12, s = row & 4095;
        size_t qi = ((size_t)(b * HH + h) * SEQ + s) * 64 + d;
        Q[qi] = aq[r] + biasq;
        K[qi] = ak[r] + biask;
        V[qi] = av[r] + biasv;
    }
}

// ---- pass 1: per-column (over queries i) max & sum-exp of s_ij ----
// grid (8 jblk, 8 isplit, 8 bh); thread owns 2 j rows of K in registers.
__global__ __launch_bounds__(256) void k_colstats(float* __restrict__ ws) {
    __shared__ float qs[64 * 64];
    int t = threadIdx.x;
    int bx = blockIdx.x, iy = blockIdx.y, bh = blockIdx.z;
    const float* Q = ws + OFF_Q;
    const float* K = ws + OFF_K;
    int j0 = bx * 512 + 2 * t;
    const float4* Kp = (const float4*)(K + ((size_t)bh * SEQ + j0) * 64);
    float k0[64], k1[64];
#pragma unroll
    for (int dg = 0; dg < 16; dg++) {
        float4 a = Kp[dg];
        k0[dg * 4 + 0] = a.x; k0[dg * 4 + 1] = a.y; k0[dg * 4 + 2] = a.z; k0[dg * 4 + 3] = a.w;
        float4 c = Kp[16 + dg];
        k1[dg * 4 + 0] = c.x; k1[dg * 4 + 1] = c.y; k1[dg * 4 + 2] = c.z; k1[dg * 4 + 3] = c.w;
    }
    float m0 = -1e30f, z0 = 0.f, m1 = -1e30f, z1 = 0.f;
    for (int it = 0; it < 8; it++) {
        int i0 = iy * 512 + it * 64;
        __syncthreads();
        const float4* Qp = (const float4*)(Q + ((size_t)bh * SEQ + i0) * 64);
        for (int c = t; c < 1024; c += 256) ((float4*)qs)[c] = Qp[c];
        __syncthreads();
        for (int ii = 0; ii < 64; ii++) {
            float s0a = 0.f, s0b = 0.f, s1a = 0.f, s1b = 0.f;
#pragma unroll
            for (int dg = 0; dg < 16; dg++) {
                float4 q = *(const float4*)(qs + ii * 64 + dg * 4);
                s0a += q.x * k0[dg * 4] + q.y * k0[dg * 4 + 1];
                s0b += q.z * k0[dg * 4 + 2] + q.w * k0[dg * 4 + 3];
                s1a += q.x * k1[dg * 4] + q.y * k1[dg * 4 + 1];
                s1b += q.z * k1[dg * 4 + 2] + q.w * k1[dg * 4 + 3];
            }
            float s0 = (s0a + s0b) * SCALE, s1 = (s1a + s1b) * SCALE;
            float nm0 = fmaxf(m0, s0);
            z0 = z0 * __expf(m0 - nm0) + __expf(s0 - nm0); m0 = nm0;
            float nm1 = fmaxf(m1, s1);
            z1 = z1 * __expf(m1 - nm1) + __expf(s1 - nm1); m1 = nm1;
        }
    }
    float* pm = ws + OFF_PM;
    float* pz = ws + OFF_PZ;
    size_t o = (size_t)iy * 32768 + (size_t)bh * SEQ + j0;
    pm[o] = m0; pz[o] = z0; pm[o + 1] = m1; pz[o + 1] = z1;
}

// ---- pass 1b: combine the 8 i-range partials ----
__global__ void k_combine(float* __restrict__ ws) {
    int idx = blockIdx.x * 256 + threadIdx.x;  // 0..32767
    const float* pm = ws + OFF_PM;
    const float* pz = ws + OFF_PZ;
    float m = -1e30f;
#pragma unroll
    for (int iy = 0; iy < 8; iy++) m = fmaxf(m, pm[(size_t)iy * 32768 + idx]);
    float z = 0.f;
#pragma unroll
    for (int iy = 0; iy < 8; iy++)
        z += pz[(size_t)iy * 32768 + idx] * __expf(pm[(size_t)iy * 32768 + idx] - m);
    ws[OFF_M + idx] = m;
    ws[OFF_RZ + idx] = 1.0f / z;
}

// ---- pass 2: out_i += sum_{j in quarter} exp(s_ij - m_j)*rz_j * v_j ----
// grid (16 iblk, 4 jsplit, 8 bh); thread owns 1 query row; atomicAdd into AO.
__global__ __launch_bounds__(256) void k_attnpv(float* __restrict__ ws) {
    __shared__ float ks[4096], vs[4096], msh[64], rzh[64];
    int t = threadIdx.x;
    int ib = blockIdx.x, jy = blockIdx.y, bh = blockIdx.z;
    const float* Q = ws + OFF_Q;
    const float* K = ws + OFF_K;
    const float* V = ws + OFF_V;
    const float* mcol = ws + OFF_M;
    const float* rzcol = ws + OFF_RZ;
    int i = ib * 256 + t;
    float qr[64];
    const float4* Qp = (const float4*)(Q + ((size_t)bh * SEQ + i) * 64);
#pragma unroll
    for (int dg = 0; dg < 16; dg++) {
        float4 a = Qp[dg];
        qr[dg * 4 + 0] = a.x; qr[dg * 4 + 1] = a.y; qr[dg * 4 + 2] = a.z; qr[dg * 4 + 3] = a.w;
    }
    float o[64];
#pragma unroll
    for (int d = 0; d < 64; d++) o[d] = 0.f;

    for (int jt = 0; jt < 1024; jt += 64) {
        int j0 = jy * 1024 + jt;
        __syncthreads();
        const float4* Kp = (const float4*)(K + ((size_t)bh * SEQ + j0) * 64);
        const float4* Vp = (const float4*)(V + ((size_t)bh * SEQ + j0) * 64);
        for (int c = t; c < 1024; c += 256) {
            ((float4*)ks)[c] = Kp[c];
            ((float4*)vs)[c] = Vp[c];
        }
        if (t < 64) {
            msh[t] = mcol[(size_t)bh * SEQ + j0 + t];
            rzh[t] = rzcol[(size_t)bh * SEQ + j0 + t];
        }
        __syncthreads();
        for (int jj = 0; jj < 64; jj++) {
            float sa = 0.f, sb = 0.f;
#pragma unroll
            for (int dg = 0; dg < 16; dg++) {
                float4 kv = *(const float4*)(ks + jj * 64 + dg * 4);
                sa += kv.x * qr[dg * 4] + kv.y * qr[dg * 4 + 1];
                sb += kv.z * qr[dg * 4 + 2] + kv.w * qr[dg * 4 + 3];
            }
            float p = __expf((sa + sb) * SCALE - msh[jj]) * rzh[jj];
#pragma unroll
            for (int dg = 0; dg < 16; dg++) {
                float4 vv = *(const float4*)(vs + jj * 64 + dg * 4);
                o[dg * 4 + 0] += p * vv.x;
                o[dg * 4 + 1] += p * vv.y;
                o[dg * 4 + 2] += p * vv.z;
                o[dg * 4 + 3] += p * vv.w;
            }
        }
    }
    int b = bh >> 2, h = bh & 3;
    float* ao = ws + OFF_AO + ((size_t)(b * SEQ + i)) * 256 + h * 64;
#pragma unroll
    for (int d = 0; d < 64; d++) atomicAdd(&ao[d], o[d]);
}

// ---- output projection: AO @ wo.T + bo, FP32 out ----
__global__ __launch_bounds__(256) void k_outproj(const float* __restrict__ bo,
                                                 const float* __restrict__ ws,
                                                 float* __restrict__ out) {
    __shared__ float xs[16 * 256];
    int t = threadIdx.x;
    int row0 = blockIdx.x * 16;
    const float* ao = ws + OFF_AO;
    const float* woT = ws + OFF_WOT;
    const float4* src = (const float4*)(ao + (size_t)row0 * 256);
    for (int c = t; c < 1024; c += 256) ((float4*)xs)[c] = src[c];
    __syncthreads();
    float acc[16];
#pragma unroll
    for (int r = 0; r < 16; r++) acc[r] = 0.f;
    for (int kk = 0; kk < 256; kk += 4) {
        float w0 = woT[(kk + 0) * 256 + t], w1 = woT[(kk + 1) * 256 + t];
        float w2 = woT[(kk + 2) * 256 + t], w3 = woT[(kk + 3) * 256 + t];
#pragma unroll
        for (int r = 0; r < 16; r++) {
            float4 xv = *(const float4*)(xs + r * 256 + kk);
            acc[r] += xv.x * w0 + xv.y * w1 + xv.z * w2 + xv.w * w3;
        }
    }
    float bias = bo[t];
#pragma unroll
    for (int r = 0; r < 16; r++)
        out[(size_t)(row0 + r) * 256 + t] = acc[r] + bias;
}

extern "C" void kernel_launch(void* const* d_in, const int* in_sizes, int n_in,
                              void* d_out, int out_size, void* d_ws, size_t ws_size,
                              hipStream_t stream) {
    const float* x  = (const float*)d_in[0];
    const float* wq = (const float*)d_in[1];
    const float* bq = (const float*)d_in[2];
    const float* wk = (const float*)d_in[3];
    const float* bk = (const float*)d_in[4];
    const float* wv = (const float*)d_in[5];
    const float* bv = (const float*)d_in[6];
    const float* wo = (const float*)d_in[7];
    const float* bo = (const float*)d_in[8];
    float* ws = (float*)d_ws;
    float* out = (float*)d_out;

    k_zero<<<2048, 256, 0, stream>>>(ws);
    k_transpose<<<dim3(256, 4), 256, 0, stream>>>(wq, wk, wv, wo, ws);
    k_qkv<<<512, 256, 0, stream>>>(x, bq, bk, bv, ws);
    k_colstats<<<dim3(8, 8, 8), 256, 0, stream>>>(ws);
    k_combine<<<128, 256, 0, stream>>>(ws);
    k_attnpv<<<dim3(16, 4, 8), 256, 0, stream>>>(ws);
    k_outproj<<<512, 256, 0, stream>>>(bo, ws, out);
}

// Round 8
// 587.215 us; speedup vs baseline: 3.8504x; 3.8504x over previous
//
#include <hip/hip_runtime.h>

#define SEQ   4096
#define HH    4
#define SCALE 0.125f

typedef __bf16 bf16x8 __attribute__((ext_vector_type(8)));
typedef float  f32x4  __attribute__((ext_vector_type(4)));

// ---- ws layout (float offsets), total 23.3 MB (< proven 70.5 MB) ----
// Facts: inputs fp32, OUTPUT fp32 (R6 probe), ws >= 70.5 MB (R2==R3).
constexpr size_t OFF_WQT = 0;        // transposed weights, 65536 each
constexpr size_t OFF_WKT = 65536;
constexpr size_t OFF_WVT = 131072;
constexpr size_t OFF_WOT = 196608;
constexpr size_t OFF_M   = 262144;   // [bh*S+j] column max
constexpr size_t OFF_RZ  = 294912;   // [bh*S+j] 1/Z
constexpr size_t OFF_PM  = 327680;   // [4][32768]
constexpr size_t OFF_PZ  = 458752;   // [4][32768]
constexpr size_t OFF_AO  = 589824;   // [b*S+i][256] fp32
constexpr size_t OFF_Q16 = 2686976;  // bf16 region (float offset)
constexpr size_t K16OFF  = 2097152;  // bf16-element offsets in region
constexpr size_t V16OFF  = 4194304;  // V stored TRANSPOSED [bh][d][s]

__device__ __forceinline__ f32x4 mf(bf16x8 a, bf16x8 b, f32x4 c) {
    return __builtin_amdgcn_mfma_f32_16x16x32_bf16(a, b, c, 0, 0, 0);
}

// ---- transpose weights to [k][n] fp32 ----
__global__ void k_transpose(const float* __restrict__ wq, const float* __restrict__ wk,
                            const float* __restrict__ wv, const float* __restrict__ wo,
                            float* __restrict__ ws) {
    int kk = blockIdx.x, t = threadIdx.x, y = blockIdx.y;
    const float* src = (y == 0) ? wq : (y == 1) ? wk : (y == 2) ? wv : wo;
    ws[(size_t)y * 65536 + kk * 256 + t] = src[(size_t)t * 256 + kk];
}

// ---- QKV projection (fp32 math, bf16 stores; V transposed) ----
__global__ __launch_bounds__(256) void k_qkv(const float* __restrict__ x,
                                             const float* __restrict__ bq,
                                             const float* __restrict__ bk,
                                             const float* __restrict__ bv,
                                             float* __restrict__ ws) {
    __shared__ float xs[16 * 768];
    const float* wqT = ws + OFF_WQT;
    const float* wkT = ws + OFF_WKT;
    const float* wvT = ws + OFF_WVT;
    __bf16* Q16 = (__bf16*)(ws + OFF_Q16);
    __bf16* K16 = Q16 + K16OFF;
    __bf16* V16 = Q16 + V16OFF;
    int t = threadIdx.x;
    int row0 = blockIdx.x * 16;
    for (int idx = t; idx < 16 * 768; idx += 256)
        xs[idx] = x[(size_t)row0 * 768 + idx];
    __syncthreads();

    float aq[16], ak[16], av[16];
#pragma unroll
    for (int r = 0; r < 16; r++) { aq[r] = 0.f; ak[r] = 0.f; av[r] = 0.f; }

    for (int kk = 0; kk < 256; kk += 4) {
        float wq0 = wqT[(kk + 0) * 256 + t], wq1 = wqT[(kk + 1) * 256 + t];
        float wq2 = wqT[(kk + 2) * 256 + t], wq3 = wqT[(kk + 3) * 256 + t];
        float wk0 = wkT[(kk + 0) * 256 + t], wk1 = wkT[(kk + 1) * 256 + t];
        float wk2 = wkT[(kk + 2) * 256 + t], wk3 = wkT[(kk + 3) * 256 + t];
        float wv0 = wvT[(kk + 0) * 256 + t], wv1 = wvT[(kk + 1) * 256 + t];
        float wv2 = wvT[(kk + 2) * 256 + t], wv3 = wvT[(kk + 3) * 256 + t];
#pragma unroll
        for (int r = 0; r < 16; r++) {
            float4 xq = *(const float4*)(xs + r * 768 + kk);
            float4 xk = *(const float4*)(xs + r * 768 + 256 + kk);
            float4 xv = *(const float4*)(xs + r * 768 + 512 + kk);
            aq[r] += xq.x * wq0 + xq.y * wq1 + xq.z * wq2 + xq.w * wq3;
            ak[r] += xk.x * wk0 + xk.y * wk1 + xk.z * wk2 + xk.w * wk3;
            av[r] += xv.x * wv0 + xv.y * wv1 + xv.z * wv2 + xv.w * wv3;
        }
    }
    float biasq = bq[t], biask = bk[t], biasv = bv[t];
    int h = t >> 6, d = t & 63;
#pragma unroll
    for (int r = 0; r < 16; r++) {
        int row = row0 + r;
        int b = row >> 12, s = row & 4095;
        int bh = b * HH + h;
        Q16[((size_t)bh * SEQ + s) * 64 + d] = (__bf16)(aq[r] + biasq);
        K16[((size_t)bh * SEQ + s) * 64 + d] = (__bf16)(ak[r] + biask);
        V16[((size_t)bh * 64 + d) * SEQ + s] = (__bf16)(av[r] + biasv);
    }
}

// ---- pass 1 (MFMA): per-column (over i) max & sum-exp ----
// grid (64 jblk, 4 isplit, 8 bh); wave owns 16 j, streams 1024 i.
__global__ __launch_bounds__(256) void k_colstats(float* __restrict__ ws) {
    int t = threadIdx.x, lane = t & 63, w = t >> 6;
    int jb = blockIdx.x, iy = blockIdx.y, bh = blockIdx.z;
    int j0 = jb * 64 + w * 16;
    int mrow = lane & 15, quad = lane >> 4;
    const __bf16* Q16 = (const __bf16*)(ws + OFF_Q16);
    const __bf16* K16 = Q16 + K16OFF;
    const __bf16* kb = K16 + ((size_t)bh * SEQ + j0 + mrow) * 64 + quad * 8;
    bf16x8 bk0 = *(const bf16x8*)(kb);
    bf16x8 bk1 = *(const bf16x8*)(kb + 32);
    const __bf16* qb = Q16 + ((size_t)bh * SEQ + iy * 1024 + mrow) * 64 + quad * 8;
    float m = -1e30f, z = 0.f;
    for (int ic = 0; ic < 64; ic++) {
        const __bf16* qp = qb + (size_t)ic * 16 * 64;
        bf16x8 aq0 = *(const bf16x8*)(qp);
        bf16x8 aq1 = *(const bf16x8*)(qp + 32);
        f32x4 c = {0.f, 0.f, 0.f, 0.f};
        c = mf(aq0, bk0, c);
        c = mf(aq1, bk1, c);
        float s0 = c[0] * SCALE, s1 = c[1] * SCALE;
        float s2 = c[2] * SCALE, s3 = c[3] * SCALE;
        float smax = fmaxf(fmaxf(s0, s1), fmaxf(s2, s3));
        float nm = fmaxf(m, smax);
        z = z * __expf(m - nm) + __expf(s0 - nm) + __expf(s1 - nm)
          + __expf(s2 - nm) + __expf(s3 - nm);
        m = nm;
    }
    // merge across quads (lanes sharing lane&15 hold same j, different i)
#pragma unroll
    for (int off = 16; off < 64; off <<= 1) {
        float mo = __shfl_xor(m, off, 64);
        float zo = __shfl_xor(z, off, 64);
        float nm = fmaxf(m, mo);
        z = z * __expf(m - nm) + zo * __expf(mo - nm);
        m = nm;
    }
    if (lane < 16) {
        size_t o = (size_t)iy * 32768 + (size_t)bh * SEQ + j0 + lane;
        ws[OFF_PM + o] = m;
        ws[OFF_PZ + o] = z;
    }
}

// ---- pass 1b: combine the 4 i-range partials ----
__global__ void k_combine(float* __restrict__ ws) {
    int idx = blockIdx.x * 256 + threadIdx.x;  // 0..32767
    const float* pm = ws + OFF_PM;
    const float* pz = ws + OFF_PZ;
    float m = -1e30f;
#pragma unroll
    for (int iy = 0; iy < 4; iy++) m = fmaxf(m, pm[(size_t)iy * 32768 + idx]);
    float z = 0.f;
#pragma unroll
    for (int iy = 0; iy < 4; iy++)
        z += pz[(size_t)iy * 32768 + idx] * __expf(pm[(size_t)iy * 32768 + idx] - m);
    ws[OFF_M + idx] = m;
    ws[OFF_RZ + idx] = 1.0f / z;
}

// ---- pass 2 (MFMA): O[i][d] = sum_j exp(s_ij - m_j) * rz_j * V[j][d] ----
// grid (64 iblk, 8 bh); wave owns 16 i, streams all 4096 j in 32-chunks.
// P goes C-layout -> LDS [i][j] tile -> A-layout (per-wave 1KB, no barriers).
__global__ __launch_bounds__(256) void k_attnpv(float* __restrict__ ws) {
    __shared__ __bf16 ptile[4 * 512];
    int t = threadIdx.x, lane = t & 63, w = t >> 6;
    int bh = blockIdx.y;
    int i0 = blockIdx.x * 64 + w * 16;
    int mrow = lane & 15, quad = lane >> 4;
    const __bf16* Q16 = (const __bf16*)(ws + OFF_Q16);
    const __bf16* K16 = Q16 + K16OFF;
    const __bf16* V16 = Q16 + V16OFF;
    const float* Mc  = ws + OFF_M  + (size_t)bh * SEQ;
    const float* RZc = ws + OFF_RZ + (size_t)bh * SEQ;
    __bf16* pt = ptile + w * 512;

    const __bf16* qb = Q16 + ((size_t)bh * SEQ + i0 + mrow) * 64 + quad * 8;
    bf16x8 aq0 = *(const bf16x8*)(qb);
    bf16x8 aq1 = *(const bf16x8*)(qb + 32);

    f32x4 oacc[2][4];
#pragma unroll
    for (int pp = 0; pp < 2; pp++)
#pragma unroll
        for (int nd = 0; nd < 4; nd++) oacc[pp][nd] = {0.f, 0.f, 0.f, 0.f};

    for (int j0 = 0; j0 < SEQ; j0 += 32) {
        const __bf16* kb = K16 + ((size_t)bh * SEQ + j0 + mrow) * 64 + quad * 8;
#pragma unroll
        for (int nt = 0; nt < 2; nt++) {
            bf16x8 bk0 = *(const bf16x8*)(kb + (size_t)nt * 16 * 64);
            bf16x8 bk1 = *(const bf16x8*)(kb + (size_t)nt * 16 * 64 + 32);
            f32x4 c = {0.f, 0.f, 0.f, 0.f};
            c = mf(aq0, bk0, c);
            c = mf(aq1, bk1, c);
            int j = j0 + nt * 16 + mrow;
            float mj = Mc[j], rzj = RZc[j];
#pragma unroll
            for (int r = 0; r < 4; r++) {
                float p = __expf(c[r] * SCALE - mj) * rzj;
                pt[(quad * 4 + r) * 32 + nt * 16 + mrow] = (__bf16)p;
            }
        }
        // C-layout -> A-layout via per-wave LDS tile (same-wave dep, no barrier)
        bf16x8 ap = *(const bf16x8*)(pt + mrow * 32 + quad * 8);
        const __bf16* vb = V16 + ((size_t)bh * 64 + mrow) * SEQ + j0 + quad * 8;
        int pp = (j0 >> 5) & 1;
#pragma unroll
        for (int nd = 0; nd < 4; nd++) {
            bf16x8 bv = *(const bf16x8*)(vb + (size_t)nd * 16 * SEQ);
            oacc[pp][nd] = mf(ap, bv, oacc[pp][nd]);
        }
    }

    int b = bh >> 2, h = bh & 3;
#pragma unroll
    for (int nd = 0; nd < 4; nd++) {
#pragma unroll
        for (int r = 0; r < 4; r++) {
            float v = oacc[0][nd][r] + oacc[1][nd][r];
            int i = i0 + quad * 4 + r;
            int d = nd * 16 + mrow;
            ws[OFF_AO + ((size_t)(b * SEQ + i)) * 256 + h * 64 + d] = v;
        }
    }
}

// ---- output projection: AO @ wo.T + bo, fp32 out ----
__global__ __launch_bounds__(256) void k_outproj(const float* __restrict__ bo,
                                                 const float* __restrict__ ws,
                                                 float* __restrict__ out) {
    __shared__ float xs[16 * 256];
    int t = threadIdx.x;
    int row0 = blockIdx.x * 16;
    const float* ao = ws + OFF_AO;
    const float* woT = ws + OFF_WOT;
    const float4* src = (const float4*)(ao + (size_t)row0 * 256);
    for (int c = t; c < 1024; c += 256) ((float4*)xs)[c] = src[c];
    __syncthreads();
    float acc[16];
#pragma unroll
    for (int r = 0; r < 16; r++) acc[r] = 0.f;
    for (int kk = 0; kk < 256; kk += 4) {
        float w0 = woT[(kk + 0) * 256 + t], w1 = woT[(kk + 1) * 256 + t];
        float w2 = woT[(kk + 2) * 256 + t], w3 = woT[(kk + 3) * 256 + t];
#pragma unroll
        for (int r = 0; r < 16; r++) {
            float4 xv = *(const float4*)(xs + r * 256 + kk);
            acc[r] += xv.x * w0 + xv.y * w1 + xv.z * w2 + xv.w * w3;
        }
    }
    float bias = bo[t];
#pragma unroll
    for (int r = 0; r < 16; r++)
        out[(size_t)(row0 + r) * 256 + t] = acc[r] + bias;
}

extern "C" void kernel_launch(void* const* d_in, const int* in_sizes, int n_in,
                              void* d_out, int out_size, void* d_ws, size_t ws_size,
                              hipStream_t stream) {
    const float* x  = (const float*)d_in[0];
    const float* wq = (const float*)d_in[1];
    const float* bq = (const float*)d_in[2];
    const float* wk = (const float*)d_in[3];
    const float* bk = (const float*)d_in[4];
    const float* wv = (const float*)d_in[5];
    const float* bv = (const float*)d_in[6];
    const float* wo = (const float*)d_in[7];
    const float* bo = (const float*)d_in[8];
    float* ws = (float*)d_ws;
    float* out = (float*)d_out;

    k_transpose<<<dim3(256, 4), 256, 0, stream>>>(wq, wk, wv, wo, ws);
    k_qkv<<<512, 256, 0, stream>>>(x, bq, bk, bv, ws);
    k_colstats<<<dim3(64, 4, 8), 256, 0, stream>>>(ws);
    k_combine<<<128, 256, 0, stream>>>(ws);
    k_attnpv<<<dim3(64, 8), 256, 0, stream>>>(ws);
    k_outproj<<<512, 256, 0, stream>>>(bo, ws, out);
}